// Round 1
// baseline (226.785 us; speedup 1.0000x reference)
//
#include <hip/hip_runtime.h>

#define T_STEPS 256
#define IMG_H 512
#define IMG_W 512
#define HW (IMG_H * IMG_W)
#define TH 16
#define TW 64
#define HTH (TH + 4)              // 20
#define HTW (TW + 4)              // 68
#define HALO_N (HTH * HTW)        // 1360
#define NTHREADS 256
#define NSTAGE ((HALO_N + NTHREADS - 1) / NTHREADS)  // 6

// out[t] = 0.8*out[t-1] + conv(x)[t-1]; out[0]=0 — conv and LI scan commute.
__launch_bounds__(NTHREADS)
__global__ void conv_li_kernel(const float* __restrict__ x,
                               const float* __restrict__ kern,
                               float* __restrict__ out) {
    __shared__ float lds[2][HALO_N];

    const int tid = threadIdx.x;
    const int bx = blockIdx.x;    // tile col index (0..7)
    const int by = blockIdx.y;    // tile row index (0..31)

    // 5x5 kernel weights — wave-uniform, lands in SGPRs.
    float kw[25];
#pragma unroll
    for (int q = 0; q < 25; ++q) kw[q] = kern[q];

    // Staging geometry is t-invariant: element e -> (r,c) in halo tile.
    size_t goff[NSTAGE];
    bool gok[NSTAGE];
#pragma unroll
    for (int q = 0; q < NSTAGE; ++q) {
        int e = tid + q * NTHREADS;
        int r = e / HTW;
        int c = e - r * HTW;
        int gy = by * TH + r - 2;
        int gx = bx * TW + c - 2;
        bool ok = (e < HALO_N) && (gy >= 0) && (gy < IMG_H) && (gx >= 0) && (gx < IMG_W);
        gok[q] = ok;
        goff[q] = ok ? ((size_t)gy * IMG_W + gx) : 0;
    }

    // Each thread: column j, 4 consecutive rows starting at i0.
    const int j = tid & (TW - 1);
    const int i0 = (tid >> 6) * 4;

    float st[4] = {0.f, 0.f, 0.f, 0.f};
    const size_t out_base = (size_t)(by * TH) * IMG_W + (size_t)bx * TW;

    float rA[NSTAGE], rB[NSTAGE];

    auto LOAD = [&](float* rv, int t) {
#pragma unroll
        for (int q = 0; q < NSTAGE; ++q)
            rv[q] = gok[q] ? x[goff[q] + (size_t)t * HW] : 0.f;
    };
    auto WRITE_LDS = [&](int buf, const float* rv) {
#pragma unroll
        for (int q = 0; q < NSTAGE; ++q) {
            int e = tid + q * NTHREADS;
            if (e < HALO_N) lds[buf][e] = rv[q];
        }
    };
    auto STEP = [&](int buf, int t) {
        float acc[4] = {0.f, 0.f, 0.f, 0.f};
#pragma unroll
        for (int hr = 0; hr < 8; ++hr) {
            float seg[5];
#pragma unroll
            for (int dx = 0; dx < 5; ++dx)
                seg[dx] = lds[buf][(i0 + hr) * HTW + j + dx];
#pragma unroll
            for (int r = 0; r < 4; ++r) {
                int dy = hr - r;
                if (dy >= 0 && dy < 5) {
#pragma unroll
                    for (int dx = 0; dx < 5; ++dx)
                        acc[r] = fmaf(kw[dy * 5 + dx], seg[dx], acc[r]);
                }
            }
        }
        float* op = out + (size_t)t * HW + out_base;
#pragma unroll
        for (int r = 0; r < 4; ++r) {
            op[(size_t)(i0 + r) * IMG_W + j] = st[r];           // out[t] = S_{t-1}
            st[r] = st[r] - 0.2f * st[r] + acc[r];              // S_t = 0.8*S_{t-1} + y[t]
        }
    };

    // Prologue: rA<-tile0, rB<-tile1, stage tile0 into lds[0].
    LOAD(rA, 0);
    LOAD(rB, 1);
    WRITE_LDS(0, rA);
    __syncthreads();

    int t = 0;
    while (true) {
        // even t: compute from lds[0]; rA free -> prefetch t+2; rB -> lds[1]
        if (t + 2 < T_STEPS) LOAD(rA, t + 2);
        STEP(0, t);
        if (t + 1 < T_STEPS) WRITE_LDS(1, rB);
        __syncthreads();
        ++t;
        if (t >= T_STEPS) break;

        // odd t: compute from lds[1]; rB free -> prefetch t+2; rA -> lds[0]
        if (t + 2 < T_STEPS) LOAD(rB, t + 2);
        STEP(1, t);
        if (t + 1 < T_STEPS) WRITE_LDS(0, rA);
        __syncthreads();
        ++t;
        if (t >= T_STEPS) break;
    }
}

extern "C" void kernel_launch(void* const* d_in, const int* in_sizes, int n_in,
                              void* d_out, int out_size, void* d_ws, size_t ws_size,
                              hipStream_t stream) {
    const float* x = (const float*)d_in[0];      // [256,1,512,512] f32
    const float* kern = (const float*)d_in[1];   // [5,5] f32
    float* out = (float*)d_out;                  // [256,1,512,512] f32

    dim3 grid(IMG_W / TW, IMG_H / TH);           // (8, 32) = 256 blocks
    dim3 block(NTHREADS);
    conv_li_kernel<<<grid, block, 0, stream>>>(x, kern, out);
}